// Round 5
// baseline (563.180 us; speedup 1.0000x reference)
//
#include <hip/hip_runtime.h>

typedef unsigned short u16;
typedef unsigned int u32;

typedef __attribute__((ext_vector_type(8))) short bf16x8;
typedef __attribute__((ext_vector_type(4))) float f32x4;

#define B_ 8
#define S_ 2048
#define H_ 8
#define ID_ 256
#define OD_ 256
#define K_ 512
#define M_ (B_*S_*H_)   /* 131072 */
#define N1_ 768
#define N2_ 256
#define G2_ 512          /* activated-gate tensor width: [ig(256) | f(256)] fp16 */

#define CSCH 64            /* cumsum chunks over S */
#define CSST (S_/CSCH)     /* 32 steps per chunk */

// ---- workspace layout (bytes) ----
#define OFF_X2   (0ull)
#define SZ_X2    ((unsigned long long)M_*K_*2)        /* 134,217,728 */
#define OFF_G    (OFF_X2 + SZ_X2)
#define SZ_G     ((unsigned long long)M_*G2_*2)       /* 134,217,728 */
#define OFF_WH   (OFF_G + SZ_G)
#define SZ_WH    ((unsigned long long)N1_*K_*2)
#define OFF_WO   (OFF_WH + SZ_WH)
#define SZ_WO    ((unsigned long long)N2_*K_*2)
#define OFF_AUX  (OFF_WO + SZ_WO)
#define SZ_AUX   ((unsigned long long)B_*CSCH*2048*4)
#define OFF_CF   (OFF_AUX + SZ_AUX)
#define SZ_CARR  ((unsigned long long)B_*H_*32*256*4)
#define OFF_CC   (OFF_CF + SZ_CARR)
#define OFF_CIN  (OFF_CC + SZ_CARR)

__device__ __forceinline__ u16 f2bf(float f) {
    union { float f; u32 u; } v; v.f = f;
    u32 u = v.u;
    u += 0x7fffu + ((u >> 16) & 1u);   // round-to-nearest-even
    return (u16)(u >> 16);
}
__device__ __forceinline__ float bf2f(u16 h) {
    union { u32 u; float f; } v; v.u = ((u32)h) << 16;
    return v.f;
}
__device__ __forceinline__ u32 pack2h(float a, float b) {
    union { _Float16 h; u16 u; } x, y;
    x.h = (_Float16)a; y.h = (_Float16)b;
    return (u32)x.u | ((u32)y.u << 16);
}
__device__ __forceinline__ float h2f(u16 u) {
    union { u16 u; _Float16 h; } v; v.u = u;
    return (float)v.h;
}
__device__ __forceinline__ float sigm(float x) {
    return 1.0f / (1.0f + __expf(-x));
}

// async 16B global->LDS DMA. LDS dest = wave-uniform base + lane*16.
__device__ __forceinline__ void gld16(const void* g, void* l) {
    __builtin_amdgcn_global_load_lds(
        (const __attribute__((address_space(1))) void*)g,
        (__attribute__((address_space(3))) void*)l, 16, 0, 0);
}

// W_hid row permutation (256-wide tiles, 8 waves of 64 cols).
// Pair tiles t=0,1 (n<512): c=n&255, wn=c>>6, jj=(c>>4)&3, l=c&15
//   o = t*128 + wn*32 + (jj&1)*16 + l
//   jj in {0,1} -> igate row o ; jj in {2,3} -> hidden row 512+o
//   => per lane: ig_o = sig(acc[jj]) * relu(acc[jj+2])  (same lane, in-register)
// F tile t=2: o = n-512 -> fgate row 256+o (natural)
__device__ __forceinline__ int whid_src_row(int n) {
    const int t = n >> 8, c = n & 255;
    if (t < 2) {
        const int wn = c >> 6, jj = (c >> 4) & 3, l = c & 15;
        const int o = t * 128 + wn * 32 + (jj & 1) * 16 + l;
        return (jj < 2) ? o : (512 + o);
    }
    return 256 + (n - 512);
}

// ---- 0: weights fp32 -> bf16 (W_hid rows permuted) ----
__global__ __launch_bounds__(256) void wconv_kernel(
    const float* __restrict__ Whid, const float* __restrict__ Wog,
    u16* __restrict__ WhB, u16* __restrict__ WoB)
{
    int idx = blockIdx.x * 256 + threadIdx.x;
    if (idx < N1_*K_) {
        const int n = idx >> 9, k = idx & 511;
        WhB[idx] = f2bf(Whid[(size_t)whid_src_row(n) * K_ + k]);
    }
    if (idx < N2_*K_) WoB[idx] = f2bf(Wog[idx]);
}

// ---- 1: cumsum phase 1 — per-(b,chunk) local totals, float4 loads ----
// thread owns 8 consecutive cols c0..c0+7 of the 2048-wide (h,d) row.
__global__ __launch_bounds__(256) void csum_phase1(
    const float* __restrict__ X, float* __restrict__ aux)
{
    const int bch = blockIdx.x;          // b*CSCH + ch
    const int b = bch / CSCH, ch = bch % CSCH;
    const int c0 = threadIdx.x * 8;
    float acc[8];
#pragma unroll
    for (int j = 0; j < 8; ++j) acc[j] = 0.f;
    for (int i = 0; i < CSST; ++i) {
        const int s = ch * CSST + i;
        const float4* xp = (const float4*)(const void*)
            (X + ((size_t)(b * S_ + s)) * 2048 + c0);
        const float4 a0 = xp[0], a1 = xp[1];
        acc[0] += a0.x; acc[1] += a0.y; acc[2] += a0.z; acc[3] += a0.w;
        acc[4] += a1.x; acc[5] += a1.y; acc[6] += a1.z; acc[7] += a1.w;
    }
    float4* ap = (float4*)(void*)(aux + (size_t)bch * 2048 + c0);
    ap[0] = make_float4(acc[0], acc[1], acc[2], acc[3]);
    ap[1] = make_float4(acc[4], acc[5], acc[6], acc[7]);
}

// ---- 2: cumsum carry — exclusive prefix over CSCH chunks, register-ized ----
// load all 64 values (independent, pipelined), scan in regs, store back.
__global__ __launch_bounds__(256) void csum_mid(float* __restrict__ aux)
{
    const int idx = blockIdx.x * 256 + threadIdx.x;
    const int b = idx >> 11, c = idx & 2047;
    float v[CSCH];
#pragma unroll
    for (int ch = 0; ch < CSCH; ++ch)
        v[ch] = aux[((size_t)(b * CSCH + ch)) * 2048 + c];
    float run = 0.f;
#pragma unroll
    for (int ch = 0; ch < CSCH; ++ch) {
        const float x = v[ch]; v[ch] = run; run += x;
    }
#pragma unroll
    for (int ch = 0; ch < CSCH; ++ch)
        aux[((size_t)(b * CSCH + ch)) * 2048 + c] = v[ch];
}

// ---- 3: cumsum phase 2 — replay + LayerNorm + pack x2 bf16 (vectorized) ----
// thread owns 8 consecutive cols (one head, 8 consecutive d) -> uint4 stores.
__global__ __launch_bounds__(256) void csum_phase2(
    const float* __restrict__ X, const float* __restrict__ aux,
    const float* __restrict__ lnw, const float* __restrict__ lnb,
    u16* __restrict__ x2)
{
    const int bch = blockIdx.x;
    const int b = bch / CSCH, ch = bch % CSCH;
    const int t = threadIdx.x;
    const int c0 = t * 8;
    const int h0 = c0 >> 8, d0 = c0 & 255;
    float c[8], wv[8], bv[8];
#pragma unroll
    for (int j = 0; j < 8; ++j) {
        c[j]  = aux[(size_t)bch * 2048 + c0 + j];
        wv[j] = lnw[c0 + j];
        bv[j] = lnb[c0 + j];
    }
    __shared__ float red[2][4];
    for (int i = 0; i < CSST; ++i) {
        const int s = ch * CSST + i;
        const float4* xp = (const float4*)(const void*)
            (X + ((size_t)(b * S_ + s)) * 2048 + c0);
        const float4 a0 = xp[0], a1 = xp[1];
        float xa[8] = {a0.x, a0.y, a0.z, a0.w, a1.x, a1.y, a1.z, a1.w};
        float sx = 0.f, sq = 0.f;
#pragma unroll
        for (int j = 0; j < 8; ++j) {
            c[j] += xa[j];
            sx += c[j]; sq += c[j] * c[j];
        }
#pragma unroll
        for (int off = 32; off >= 1; off >>= 1) {
            sx += __shfl_down(sx, (unsigned)off);
            sq += __shfl_down(sq, (unsigned)off);
        }
        const int wid = t >> 6;
        if ((t & 63) == 0) { red[0][wid] = sx; red[1][wid] = sq; }
        __syncthreads();
        const float tsx = red[0][0] + red[0][1] + red[0][2] + red[0][3];
        const float tsq = red[1][0] + red[1][1] + red[1][2] + red[1][3];
        __syncthreads();
        const float mean = tsx * (1.f / 2048.f);
        const float var  = tsq * (1.f / 2048.f) - mean * mean;
        const float rstd = rsqrtf(var + 1e-6f);
        u16* row = x2 + (((size_t)(b * S_ + s)) * H_ + h0) * (size_t)K_;
        uint4 pa, pn;
        pa.x = (u32)f2bf(xa[0]) | ((u32)f2bf(xa[1]) << 16);
        pa.y = (u32)f2bf(xa[2]) | ((u32)f2bf(xa[3]) << 16);
        pa.z = (u32)f2bf(xa[4]) | ((u32)f2bf(xa[5]) << 16);
        pa.w = (u32)f2bf(xa[6]) | ((u32)f2bf(xa[7]) << 16);
        float nv[8];
#pragma unroll
        for (int j = 0; j < 8; ++j)
            nv[j] = (c[j] - mean) * rstd * wv[j] + bv[j];
        pn.x = (u32)f2bf(nv[0]) | ((u32)f2bf(nv[1]) << 16);
        pn.y = (u32)f2bf(nv[2]) | ((u32)f2bf(nv[3]) << 16);
        pn.z = (u32)f2bf(nv[4]) | ((u32)f2bf(nv[5]) << 16);
        pn.w = (u32)f2bf(nv[6]) | ((u32)f2bf(nv[7]) << 16);
        *(uint4*)(void*)(row + d0)       = pa;
        *(uint4*)(void*)(row + 256 + d0) = pn;
    }
}

// ---- GEMM: C[m,n] = sum_k A[m,k] * W[n,k], A/W bf16 row-major (ld=512) ----
// 256x256 tile, BK=32, 512 thr = 8 waves (2M x 4N), 128x64 out per wave,
// acc[8][4] via mfma_16x16x32_bf16.
// Deep pipeline: 4-buffer LDS ring (128 KiB), depth-3 prefetch with
// global_load_lds; counted s_waitcnt vmcnt (never 0 mid-loop) + RAW s_barrier.
// (Structure identical to round 4 — gemm untouched this round.)
template<int N, int EPI>
__global__ __launch_bounds__(512, 2) void gemm_kernel(
    const u16* __restrict__ A, const u16* __restrict__ Bw,
    u16* __restrict__ Gout, const float* __restrict__ bias,
    const u16* __restrict__ cellbuf, float* __restrict__ Out)
{
    constexpr int NT = N / 256;
    constexpr int KT = K_ / 32;     // 16 K-tiles
    const int blk = blockIdx.x;
    const int xcd = blk & 7;
    const int j = blk >> 3;
    const int tileN = j % NT;
    const int tileM = (j / NT) * 8 + xcd;
    const int m0 = tileM * 256, n0 = tileN * 256;
    const int tid = threadIdx.x;
    const int lane = tid & 63;
    const int w = tid >> 6;                 // wave 0..7
    const int wm = w >> 2, wn = w & 3;      // 2 x 4
    const int l15 = lane & 15, quad = lane >> 4;

    // 4 ring buffers x (A 256x32 + B 256x32) bf16 = 4 x 32 KB = 128 KB
    __shared__ __align__(16) u16 smem[4 * 16384];

    // --- staging geometry (per thread: 2 A-loads + 2 B-loads per K-tile) ---
    const int srow   = lane >> 2;                                  // 0..15
    const int schunk = ((lane & 3) ^ ((lane >> 3) & 3)) * 8;       // swizzled src col
    const u16* gA0 = A  + (size_t)(m0 + w * 32      + srow) * K_ + schunk;
    const u16* gA1 = A  + (size_t)(m0 + w * 32 + 16 + srow) * K_ + schunk;
    const u16* gB0 = Bw + (size_t)(n0 + w * 32      + srow) * K_ + schunk;
    const u16* gB1 = Bw + (size_t)(n0 + w * 32 + 16 + srow) * K_ + schunk;

    auto STAGE_A = [&](int bufb, int kt) {
        u16* sb = smem + bufb * 16384;
        gld16(gA0 + kt * 32, sb + (w * 32) * 32);
        gld16(gA1 + kt * 32, sb + (w * 32 + 16) * 32);
    };
    auto STAGE_B = [&](int bufb, int kt) {
        u16* sb = smem + bufb * 16384;
        gld16(gB0 + kt * 32, sb + 8192 + (w * 32) * 32);
        gld16(gB1 + kt * 32, sb + 8192 + (w * 32 + 16) * 32);
    };

    // --- fragment read geometry ---
    const int swz  = (quad ^ ((l15 >> 1) & 3)) * 8;                // swizzled chunk
    const int aoff = (wm * 128 + l15) * 32 + swz;                  // + mi*512
    const int boff = 8192 + (wn * 64 + l15) * 32 + swz;            // + jj*512

    f32x4 acc[8][4];
    const f32x4 zero4 = {0.f, 0.f, 0.f, 0.f};
#pragma unroll
    for (int mi = 0; mi < 8; ++mi)
#pragma unroll
        for (int jj = 0; jj < 4; ++jj) acc[mi][jj] = zero4;

    // prologue: stage tiles 0,1,2; wait tile 0 (8 = tiles 1,2 still in flight)
    STAGE_A(0, 0); STAGE_B(0, 0);
    STAGE_A(1, 1); STAGE_B(1, 1);
    STAGE_A(2, 2); STAGE_B(2, 2);
    asm volatile("s_waitcnt vmcnt(8)\n\ts_barrier" ::: "memory");

#pragma unroll
    for (int kt = 0; kt < KT; ++kt) {
        const int cur = kt & 3;
        const u16* sb = smem + cur * 16384;
        bf16x8 af0[4], af1[4], bfr[4];

        // ---- phase 1: issue B + A-low reads; stage A-half of kt+3 ----
#pragma unroll
        for (int jj = 0; jj < 4; ++jj)
            bfr[jj] = *(const bf16x8*)(const void*)(&sb[boff + jj * 512]);
#pragma unroll
        for (int mi = 0; mi < 4; ++mi)
            af0[mi] = *(const bf16x8*)(const void*)(&sb[aoff + mi * 512]);
        if (kt + 3 < KT) STAGE_A((kt + 3) & 3, kt + 3);
        asm volatile("s_barrier" ::: "memory");
        asm volatile("s_waitcnt lgkmcnt(0)" ::: "memory");
        __builtin_amdgcn_sched_barrier(0);
        __builtin_amdgcn_s_setprio(1);
#pragma unroll
        for (int mi = 0; mi < 4; ++mi)
#pragma unroll
            for (int jj = 0; jj < 4; ++jj)
                acc[mi][jj] = __builtin_amdgcn_mfma_f32_16x16x32_bf16(
                    af0[mi], bfr[jj], acc[mi][jj], 0, 0, 0);
        __builtin_amdgcn_s_setprio(0);
        asm volatile("s_barrier" ::: "memory");

        // ---- phase 2: issue A-high reads; stage B-half of kt+3 ----
#pragma unroll
        for (int mi = 0; mi < 4; ++mi)
            af1[mi] = *(const bf16x8*)(const void*)(&sb[aoff + (mi + 4) * 512]);
        if (kt + 3 < KT) STAGE_B((kt + 3) & 3, kt + 3);
        asm volatile("s_barrier" ::: "memory");
        asm volatile("s_waitcnt lgkmcnt(0)" ::: "memory");
        __builtin_amdgcn_sched_barrier(0);
        __builtin_amdgcn_s_setprio(1);
#pragma unroll
        for (int mi = 0; mi < 4; ++mi)
#pragma unroll
            for (int jj = 0; jj < 4; ++jj)
                acc[mi + 4][jj] = __builtin_amdgcn_mfma_f32_16x16x32_bf16(
                    af1[mi], bfr[jj], acc[mi + 4][jj], 0, 0, 0);
        __builtin_amdgcn_s_setprio(0);

        // end-of-kt: counted wait — tile kt+1 must be resident; keep deeper
        // prefetch (tiles kt+2, kt+3 = 8 loads/thread) in flight
        if (kt + 1 < KT) {
            if (kt + 3 < KT)
                asm volatile("s_waitcnt vmcnt(8)\n\ts_barrier" ::: "memory");
            else if (kt + 2 < KT)
                asm volatile("s_waitcnt vmcnt(4)\n\ts_barrier" ::: "memory");
            else
                asm volatile("s_waitcnt vmcnt(0)\n\ts_barrier" ::: "memory");
        }
    }

    // ---- epilogue (C/D layout: col=lane&15, row=quad*4+reg) — in-register ----
    const int m_base = m0 + wm * 128 + quad * 4;
    if (EPI == 0) {
        if (tileN < 2) {
            const int o0 = tileN * 128 + wn * 32 + l15;
            const float bI0 = bias[o0],            bI1 = bias[o0 + 16];
            const float bH0 = bias[512 + o0],      bH1 = bias[512 + o0 + 16];
            const int q = (tileN * 4 + wn) * 16 + l15;      // u32 slot
#pragma unroll
            for (int mi = 0; mi < 8; ++mi) {
#pragma unroll
                for (int r = 0; r < 4; ++r) {
                    const int m = m_base + mi * 16 + r;
                    const float ig0 = sigm(acc[mi][0][r] + bI0) * fmaxf(acc[mi][2][r] + bH0, 0.f);
                    const float ig1 = sigm(acc[mi][1][r] + bI1) * fmaxf(acc[mi][3][r] + bH1, 0.f);
                    *(u32*)(void*)(Gout + (size_t)m * G2_ + 2 * q) = pack2h(ig0, ig1);
                }
            }
        } else {
            const int o0 = wn * 64 + l15;
            const float bF0 = bias[256 + o0],       bF1 = bias[256 + o0 + 16];
            const float bF2 = bias[256 + o0 + 32],  bF3 = bias[256 + o0 + 48];
            const int qA = wn * 32 + l15, qB = qA + 16;
#pragma unroll
            for (int mi = 0; mi < 8; ++mi) {
#pragma unroll
                for (int r = 0; r < 4; ++r) {
                    const int m = m_base + mi * 16 + r;
                    u16* row = Gout + (size_t)m * G2_ + 256;
                    *(u32*)(void*)(row + 2 * qA) =
                        pack2h(sigm(acc[mi][0][r] + bF0), sigm(acc[mi][1][r] + bF1));
                    *(u32*)(void*)(row + 2 * qB) =
                        pack2h(sigm(acc[mi][2][r] + bF2), sigm(acc[mi][3][r] + bF3));
                }
            }
        }
    } else {
        const int colb = wn * 64 + l15;
        float bb[4];
#pragma unroll
        for (int jj = 0; jj < 4; ++jj) bb[jj] = bias[colb + jj * 16];
#pragma unroll
        for (int mi = 0; mi < 8; ++mi) {
#pragma unroll
            for (int r = 0; r < 4; ++r) {
                const int m = m_base + mi * 16 + r;
                const u16* cp = cellbuf + (size_t)m * K_ + 256 + colb;
                float* op = Out + (size_t)m * N2_ + colb;
#pragma unroll
                for (int jj = 0; jj < 4; ++jj)
                    op[jj * 16] = sigm(acc[mi][jj][r] + bb[jj]) * bf2f(cp[jj * 16]);
            }
        }
    }
}

// ---- scan phase 1: local recurrence over 64 steps; 8 values/thread ----
// g' is pre-activated fp16 in slot order; recurrence is order-agnostic, so
// carries (cF/cC/cin) stay in storage order. grid: B*H*4 blocks x 256 thr.
__global__ __launch_bounds__(256) void scan_phase1(
    const u16* __restrict__ g2, float* __restrict__ cF, float* __restrict__ cC)
{
    const int blk = blockIdx.x;              // (b*8+h)*4 + chp
    const int chp = blk & 3, bh = blk >> 2;
    const int h = bh & 7, b = bh >> 3;
    const int t = threadIdx.x;
    const int ch = chp * 8 + (t >> 5);
    const int o = (t & 31) * 8;              // storage u16 offset
    float F[8], c[8];
#pragma unroll
    for (int j = 0; j < 8; ++j) { F[j] = 1.f; c[j] = 0.f; }
    for (int i = 0; i < 64; ++i) {
        const int s = ch * 64 + i;
        const size_t m = ((size_t)(b * S_ + s)) * H_ + h;
        const u16* gp = g2 + m * G2_;
        const uint4 igp = *(const uint4*)(const void*)(gp + o);
        const uint4 fgp = *(const uint4*)(const void*)(gp + 256 + o);
        const u32 iw[4] = {igp.x, igp.y, igp.z, igp.w};
        const u32 fw[4] = {fgp.x, fgp.y, fgp.z, fgp.w};
#pragma unroll
        for (int p = 0; p < 4; ++p) {
            const float fl = h2f((u16)fw[p]), fh = h2f((u16)(fw[p] >> 16));
            c[2*p]   = fl * c[2*p]   + h2f((u16)iw[p]);         F[2*p]   *= fl;
            c[2*p+1] = fh * c[2*p+1] + h2f((u16)(iw[p] >> 16)); F[2*p+1] *= fh;
        }
    }
    const size_t idx = ((size_t)(bh * 32 + ch)) * 256 + o;
    *(float4*)(void*)(cF + idx)     = make_float4(F[0], F[1], F[2], F[3]);
    *(float4*)(void*)(cF + idx + 4) = make_float4(F[4], F[5], F[6], F[7]);
    *(float4*)(void*)(cC + idx)     = make_float4(c[0], c[1], c[2], c[3]);
    *(float4*)(void*)(cC + idx + 4) = make_float4(c[4], c[5], c[6], c[7]);
}

// ---- scan carry combine (storage order; initcx needs real o) ----
// register-ized: 64 independent loads, serial chain in regs, 32 stores.
__global__ __launch_bounds__(256) void scan_mid(
    const float* __restrict__ cF, const float* __restrict__ cC,
    const float* __restrict__ initcx, float* __restrict__ cin)
{
    const int bh = blockIdx.x;               // b*8 + h
    const int h = bh & 7;
    const int a = threadIdx.x;               // storage position
    const int q = a >> 1, hfl = a & 1;
    const int ro = ((q >> 4) << 5) + (q & 15) + (hfl << 4);  // real o
    float fa[32], ca[32], co[32];
#pragma unroll
    for (int ch = 0; ch < 32; ++ch) {
        const size_t idx = ((size_t)(bh * 32 + ch)) * 256 + a;
        fa[ch] = cF[idx];
        ca[ch] = cC[idx];
    }
    float c = initcx[h * 256 + ro];
#pragma unroll
    for (int ch = 0; ch < 32; ++ch) {
        co[ch] = c;
        c = fa[ch] * c + ca[ch];
    }
#pragma unroll
    for (int ch = 0; ch < 32; ++ch)
        cin[((size_t)(bh * 32 + ch)) * 256 + a] = co[ch];
}

// ---- scan phase 2: replay; write cell bf16 (real o order) into x2 ----
// 8 values/thread, uint4 loads; stores: cols base..base+3 and base+16..+19.
__global__ __launch_bounds__(256) void scan_phase2(
    const u16* __restrict__ g2, const float* __restrict__ cin,
    u16* __restrict__ x2)
{
    const int blk = blockIdx.x;
    const int chp = blk & 3, bh = blk >> 2;
    const int h = bh & 7, b = bh >> 3;
    const int t = threadIdx.x;
    const int ch = chp * 8 + (t >> 5);
    const int z = t & 31;
    const int o = z * 8;                     // storage u16 offset
    // storage pos 8z+i -> real o = base + (i>>1) + 16*(i&1), base=32(z>>2)+4(z&3)
    const int base = ((z >> 2) << 5) + ((z & 3) << 2);
    const size_t idx = ((size_t)(bh * 32 + ch)) * 256 + o;
    const float4 c40 = *(const float4*)(const void*)(cin + idx);
    const float4 c41 = *(const float4*)(const void*)(cin + idx + 4);
    float c[8] = {c40.x, c40.y, c40.z, c40.w, c41.x, c41.y, c41.z, c41.w};
    for (int i = 0; i < 64; ++i) {
        const int s = ch * 64 + i;
        const size_t m = ((size_t)(b * S_ + s)) * H_ + h;
        const u16* gp = g2 + m * G2_;
        const uint4 igp = *(const uint4*)(const void*)(gp + o);
        const uint4 fgp = *(const uint4*)(const void*)(gp + 256 + o);
        const u32 iw[4] = {igp.x, igp.y, igp.z, igp.w};
        const u32 fw[4] = {fgp.x, fgp.y, fgp.z, fgp.w};
#pragma unroll
        for (int p = 0; p < 4; ++p) {
            const float fl = h2f((u16)fw[p]), fh = h2f((u16)(fw[p] >> 16));
            c[2*p]   = fl * c[2*p]   + h2f((u16)iw[p]);
            c[2*p+1] = fh * c[2*p+1] + h2f((u16)(iw[p] >> 16));
        }
        u16* xr = x2 + m * K_ + 256;
        // even slots c[0],c[2],c[4],c[6] -> real cols base..base+3
        // odd  slots c[1],c[3],c[5],c[7] -> real cols base+16..base+19
        uint2 pkA, pkB;
        pkA.x = (u32)f2bf(c[0]) | ((u32)f2bf(c[2]) << 16);
        pkA.y = (u32)f2bf(c[4]) | ((u32)f2bf(c[6]) << 16);
        pkB.x = (u32)f2bf(c[1]) | ((u32)f2bf(c[3]) << 16);
        pkB.y = (u32)f2bf(c[5]) | ((u32)f2bf(c[7]) << 16);
        *(uint2*)(void*)(xr + base)      = pkA;
        *(uint2*)(void*)(xr + base + 16) = pkB;
    }
}

extern "C" void kernel_launch(void* const* d_in, const int* in_sizes, int n_in,
                              void* d_out, int out_size, void* d_ws, size_t ws_size,
                              hipStream_t stream)
{
    const float* X      = (const float*)d_in[0];
    const float* Whid   = (const float*)d_in[1];
    const float* bhid   = (const float*)d_in[2];
    const float* Wog    = (const float*)d_in[3];
    const float* bog    = (const float*)d_in[4];
    const float* lnw    = (const float*)d_in[5];
    const float* lnb    = (const float*)d_in[6];
    const float* initcx = (const float*)d_in[7];
    float* out = (float*)d_out;

    char* ws = (char*)d_ws;
    u16* x2   = (u16*)(ws + OFF_X2);
    u16* g    = (u16*)(ws + OFF_G);
    u16* WhB  = (u16*)(ws + OFF_WH);
    u16* WoB  = (u16*)(ws + OFF_WO);
    float* aux = (float*)(ws + OFF_AUX);
    float* cF  = (float*)(ws + OFF_CF);
    float* cC  = (float*)(ws + OFF_CC);
    float* cin = (float*)(ws + OFF_CIN);

    wconv_kernel<<<(N1_*K_ + 255) / 256, 256, 0, stream>>>(Whid, Wog, WhB, WoB);
    csum_phase1<<<B_ * CSCH, 256, 0, stream>>>(X, aux);
    csum_mid<<<64, 256, 0, stream>>>(aux);
    csum_phase2<<<B_ * CSCH, 256, 0, stream>>>(X, aux, lnw, lnb, x2);
    gemm_kernel<N1_, 0><<<(M_ / 256) * (N1_ / 256), 512, 0, stream>>>(
        x2, WhB, g, bhid, nullptr, nullptr);
    scan_phase1<<<B_ * H_ * 4, 256, 0, stream>>>(g, cF, cC);
    scan_mid<<<B_ * H_, 256, 0, stream>>>(cF, cC, initcx, cin);
    scan_phase2<<<B_ * H_ * 4, 256, 0, stream>>>(g, cin, x2);
    gemm_kernel<N2_, 1><<<(M_ / 256) * (N2_ / 256), 512, 0, stream>>>(
        x2, WoB, nullptr, bog, x2, out);
}

// Round 6
// 558.862 us; speedup vs baseline: 1.0077x; 1.0077x over previous
//
#include <hip/hip_runtime.h>

typedef unsigned short u16;
typedef unsigned int u32;

typedef __attribute__((ext_vector_type(8))) short bf16x8;
typedef __attribute__((ext_vector_type(4))) float f32x4;

#define B_ 8
#define S_ 2048
#define H_ 8
#define ID_ 256
#define OD_ 256
#define K_ 512
#define M_ (B_*S_*H_)   /* 131072 */
#define N1_ 768
#define N2_ 256
#define G2_ 512          /* activated-gate tensor width: [ig(256) | f(256)] fp16 */

#define CSCH 64            /* cumsum chunks over S */
#define CSST (S_/CSCH)     /* 32 steps per chunk */

// ---- workspace layout (bytes) ----
#define OFF_X2   (0ull)
#define SZ_X2    ((unsigned long long)M_*K_*2)        /* 134,217,728 */
#define OFF_G    (OFF_X2 + SZ_X2)
#define SZ_G     ((unsigned long long)M_*G2_*2)       /* 134,217,728 */
#define OFF_WH   (OFF_G + SZ_G)
#define SZ_WH    ((unsigned long long)N1_*K_*2)
#define OFF_WO   (OFF_WH + SZ_WH)
#define SZ_WO    ((unsigned long long)N2_*K_*2)
#define OFF_AUX  (OFF_WO + SZ_WO)
#define SZ_AUX   ((unsigned long long)B_*CSCH*2048*4)
#define OFF_CF   (OFF_AUX + SZ_AUX)
#define SZ_CARR  ((unsigned long long)B_*H_*32*256*4)
#define OFF_CC   (OFF_CF + SZ_CARR)
#define OFF_CIN  (OFF_CC + SZ_CARR)

__device__ __forceinline__ u16 f2bf(float f) {
    union { float f; u32 u; } v; v.f = f;
    u32 u = v.u;
    u += 0x7fffu + ((u >> 16) & 1u);   // round-to-nearest-even
    return (u16)(u >> 16);
}
__device__ __forceinline__ float bf2f(u16 h) {
    union { u32 u; float f; } v; v.u = ((u32)h) << 16;
    return v.f;
}
__device__ __forceinline__ u32 pack2h(float a, float b) {
    union { _Float16 h; u16 u; } x, y;
    x.h = (_Float16)a; y.h = (_Float16)b;
    return (u32)x.u | ((u32)y.u << 16);
}
__device__ __forceinline__ float h2f(u16 u) {
    union { u16 u; _Float16 h; } v; v.u = u;
    return (float)v.h;
}
__device__ __forceinline__ float sigm(float x) {
    return 1.0f / (1.0f + __expf(-x));
}

// async 16B global->LDS DMA. LDS dest = wave-uniform base + lane*16.
__device__ __forceinline__ void gld16(const void* g, void* l) {
    __builtin_amdgcn_global_load_lds(
        (const __attribute__((address_space(1))) void*)g,
        (__attribute__((address_space(3))) void*)l, 16, 0, 0);
}

// W_hid row permutation (256-wide tiles, 8 waves of 64 cols).
// Pair tiles t=0,1 (n<512): c=n&255, wn=c>>6, jj=(c>>4)&3, l=c&15
//   o = t*128 + wn*32 + (jj&1)*16 + l
//   jj in {0,1} -> igate row o ; jj in {2,3} -> hidden row 512+o
//   => per lane: ig_o = sig(acc[jj]) * relu(acc[jj+2])  (same lane, in-register)
// F tile t=2: o = n-512 -> fgate row 256+o (natural)
__device__ __forceinline__ int whid_src_row(int n) {
    const int t = n >> 8, c = n & 255;
    if (t < 2) {
        const int wn = c >> 6, jj = (c >> 4) & 3, l = c & 15;
        const int o = t * 128 + wn * 32 + (jj & 1) * 16 + l;
        return (jj < 2) ? o : (512 + o);
    }
    return 256 + (n - 512);
}

// ---- 0: weights fp32 -> bf16 (W_hid rows permuted) ----
__global__ __launch_bounds__(256) void wconv_kernel(
    const float* __restrict__ Whid, const float* __restrict__ Wog,
    u16* __restrict__ WhB, u16* __restrict__ WoB)
{
    int idx = blockIdx.x * 256 + threadIdx.x;
    if (idx < N1_*K_) {
        const int n = idx >> 9, k = idx & 511;
        WhB[idx] = f2bf(Whid[(size_t)whid_src_row(n) * K_ + k]);
    }
    if (idx < N2_*K_) WoB[idx] = f2bf(Wog[idx]);
}

// ---- 1: cumsum phase 1 — per-(b,chunk) local totals, float4 loads ----
__global__ __launch_bounds__(256) void csum_phase1(
    const float* __restrict__ X, float* __restrict__ aux)
{
    const int bch = blockIdx.x;          // b*CSCH + ch
    const int b = bch / CSCH, ch = bch % CSCH;
    const int c0 = threadIdx.x * 8;
    float acc[8];
#pragma unroll
    for (int j = 0; j < 8; ++j) acc[j] = 0.f;
    for (int i = 0; i < CSST; ++i) {
        const int s = ch * CSST + i;
        const float4* xp = (const float4*)(const void*)
            (X + ((size_t)(b * S_ + s)) * 2048 + c0);
        const float4 a0 = xp[0], a1 = xp[1];
        acc[0] += a0.x; acc[1] += a0.y; acc[2] += a0.z; acc[3] += a0.w;
        acc[4] += a1.x; acc[5] += a1.y; acc[6] += a1.z; acc[7] += a1.w;
    }
    float4* ap = (float4*)(void*)(aux + (size_t)bch * 2048 + c0);
    ap[0] = make_float4(acc[0], acc[1], acc[2], acc[3]);
    ap[1] = make_float4(acc[4], acc[5], acc[6], acc[7]);
}

// ---- 2: cumsum carry — exclusive prefix over CSCH chunks, register-ized ----
__global__ __launch_bounds__(256) void csum_mid(float* __restrict__ aux)
{
    const int idx = blockIdx.x * 256 + threadIdx.x;
    const int b = idx >> 11, c = idx & 2047;
    float v[CSCH];
#pragma unroll
    for (int ch = 0; ch < CSCH; ++ch)
        v[ch] = aux[((size_t)(b * CSCH + ch)) * 2048 + c];
    float run = 0.f;
#pragma unroll
    for (int ch = 0; ch < CSCH; ++ch) {
        const float x = v[ch]; v[ch] = run; run += x;
    }
#pragma unroll
    for (int ch = 0; ch < CSCH; ++ch)
        aux[((size_t)(b * CSCH + ch)) * 2048 + c] = v[ch];
}

// ---- 3: cumsum phase 2 — replay + LayerNorm + pack x2 bf16 ----
// ONE barrier per s-step via double-buffered red[] (skew is bounded by the
// single barrier: a wave cannot reach step i+2's write of red[i&1] before all
// waves passed barrier i+1, which requires all reads of red[i&1] complete).
__global__ __launch_bounds__(256) void csum_phase2(
    const float* __restrict__ X, const float* __restrict__ aux,
    const float* __restrict__ lnw, const float* __restrict__ lnb,
    u16* __restrict__ x2)
{
    const int bch = blockIdx.x;
    const int b = bch / CSCH, ch = bch % CSCH;
    const int t = threadIdx.x;
    const int c0 = t * 8;
    const int h0 = c0 >> 8, d0 = c0 & 255;
    float c[8], wv[8], bv[8];
#pragma unroll
    for (int j = 0; j < 8; ++j) {
        c[j]  = aux[(size_t)bch * 2048 + c0 + j];
        wv[j] = lnw[c0 + j];
        bv[j] = lnb[c0 + j];
    }
    __shared__ float red[2][2][4];
    for (int i = 0; i < CSST; ++i) {
        const int s = ch * CSST + i;
        const int pb = i & 1;
        const float4* xp = (const float4*)(const void*)
            (X + ((size_t)(b * S_ + s)) * 2048 + c0);
        const float4 a0 = xp[0], a1 = xp[1];
        float xa[8] = {a0.x, a0.y, a0.z, a0.w, a1.x, a1.y, a1.z, a1.w};
        float sx = 0.f, sq = 0.f;
#pragma unroll
        for (int j = 0; j < 8; ++j) {
            c[j] += xa[j];
            sx += c[j]; sq += c[j] * c[j];
        }
#pragma unroll
        for (int off = 32; off >= 1; off >>= 1) {
            sx += __shfl_down(sx, (unsigned)off);
            sq += __shfl_down(sq, (unsigned)off);
        }
        const int wid = t >> 6;
        if ((t & 63) == 0) { red[pb][0][wid] = sx; red[pb][1][wid] = sq; }
        __syncthreads();
        const float tsx = red[pb][0][0] + red[pb][0][1] + red[pb][0][2] + red[pb][0][3];
        const float tsq = red[pb][1][0] + red[pb][1][1] + red[pb][1][2] + red[pb][1][3];
        const float mean = tsx * (1.f / 2048.f);
        const float var  = tsq * (1.f / 2048.f) - mean * mean;
        const float rstd = rsqrtf(var + 1e-6f);
        u16* row = x2 + (((size_t)(b * S_ + s)) * H_ + h0) * (size_t)K_;
        uint4 pa, pn;
        pa.x = (u32)f2bf(xa[0]) | ((u32)f2bf(xa[1]) << 16);
        pa.y = (u32)f2bf(xa[2]) | ((u32)f2bf(xa[3]) << 16);
        pa.z = (u32)f2bf(xa[4]) | ((u32)f2bf(xa[5]) << 16);
        pa.w = (u32)f2bf(xa[6]) | ((u32)f2bf(xa[7]) << 16);
        float nv[8];
#pragma unroll
        for (int j = 0; j < 8; ++j)
            nv[j] = (c[j] - mean) * rstd * wv[j] + bv[j];
        pn.x = (u32)f2bf(nv[0]) | ((u32)f2bf(nv[1]) << 16);
        pn.y = (u32)f2bf(nv[2]) | ((u32)f2bf(nv[3]) << 16);
        pn.z = (u32)f2bf(nv[4]) | ((u32)f2bf(nv[5]) << 16);
        pn.w = (u32)f2bf(nv[6]) | ((u32)f2bf(nv[7]) << 16);
        *(uint4*)(void*)(row + d0)       = pa;
        *(uint4*)(void*)(row + 256 + d0) = pn;
    }
}

// ---- GEMM: C[m,n] = sum_k A[m,k] * W[n,k], A/W bf16 row-major (ld=512) ----
// PERSISTENT-BLOCK version: grid = 256 blocks exactly; each block owns
// TPB = (M/256)*(N/256)/256 tiles (6 for N=768, 2 for N=256), linearized
// col-major: tg = bid*TPB + tt ; col = tg>>9, mt = tg&511 (tiles/col = 512).
// The 4-buffer LDS ring + depth-3 counted-vmcnt pipeline runs over the GLOBAL
// step index g = tt*16 + kt (GEND = TPB*16), so the pipeline never drains at
// tile boundaries: the in-register epilogue (no LDS use) overlaps the 3
// already-in-flight staged K-steps of the next tile. Inner-loop schedule is
// identical to the validated round-4/5 body.
template<int N, int EPI>
__global__ __launch_bounds__(512, 2) void gemm_kernel(
    const u16* __restrict__ A, const u16* __restrict__ Bw,
    u16* __restrict__ Gout, const float* __restrict__ bias,
    const u16* __restrict__ cellbuf, float* __restrict__ Out)
{
    constexpr int NT = N / 256;
    constexpr int MT = M_ / 256;            // 512 (pow2: col = tg>>9, mt = tg&511)
    constexpr int TPB = (NT * MT) / 256;    // 6 or 2
    constexpr int GEND = TPB * 16;          // 96 or 32

    const int bid = blockIdx.x;
    const int tid = threadIdx.x;
    const int lane = tid & 63;
    const int w = tid >> 6;                 // wave 0..7
    const int wm = w >> 2, wn = w & 3;      // 2 x 4
    const int l15 = lane & 15, quad = lane >> 4;

    // 4 ring buffers x (A 256x32 + B 256x32) bf16 = 4 x 32 KB = 128 KB
    __shared__ __align__(16) u16 smem[4 * 16384];

    const int srow   = lane >> 2;                                  // 0..15
    const int schunk = ((lane & 3) ^ ((lane >> 3) & 3)) * 8;       // swizzled src col

    auto STAGE_A = [&](int g) {
        const int tg = bid * TPB + (g >> 4);
        const int mt = tg & 511;
        const int kof = (g & 15) * 32 + schunk;
        u16* sb = smem + (g & 3) * 16384;
        const u16* a0 = A + (size_t)(mt * 256 + w * 32 + srow) * K_ + kof;
        gld16(a0,           sb + (w * 32) * 32);
        gld16(a0 + 16 * K_, sb + (w * 32 + 16) * 32);
    };
    auto STAGE_B = [&](int g) {
        const int tg = bid * TPB + (g >> 4);
        const int col = tg >> 9;
        const int kof = (g & 15) * 32 + schunk;
        u16* sb = smem + (g & 3) * 16384;
        const u16* b0 = Bw + (size_t)(col * 256 + w * 32 + srow) * K_ + kof;
        gld16(b0,           sb + 8192 + (w * 32) * 32);
        gld16(b0 + 16 * K_, sb + 8192 + (w * 32 + 16) * 32);
    };

    // --- fragment read geometry ---
    const int swz  = (quad ^ ((l15 >> 1) & 3)) * 8;                // swizzled chunk
    const int aoff = (wm * 128 + l15) * 32 + swz;                  // + mi*512
    const int boff = 8192 + (wn * 64 + l15) * 32 + swz;            // + jj*512

    f32x4 acc[8][4];
    const f32x4 zero4 = {0.f, 0.f, 0.f, 0.f};

    // prologue: stage steps 0,1,2; wait step 0 (8 = steps 1,2 still in flight)
    STAGE_A(0); STAGE_B(0);
    STAGE_A(1); STAGE_B(1);
    STAGE_A(2); STAGE_B(2);
    asm volatile("s_waitcnt vmcnt(8)\n\ts_barrier" ::: "memory");

#pragma unroll 1
    for (int tt = 0; tt < TPB; ++tt) {
#pragma unroll
        for (int mi = 0; mi < 8; ++mi)
#pragma unroll
            for (int jj = 0; jj < 4; ++jj) acc[mi][jj] = zero4;

#pragma unroll
        for (int kt = 0; kt < 16; ++kt) {
            const int g = tt * 16 + kt;
            const u16* sb = smem + (g & 3) * 16384;
            bf16x8 af0[4], af1[4], bfr[4];

            // ---- phase 1: issue B + A-low reads; stage A-half of g+3 ----
#pragma unroll
            for (int jj = 0; jj < 4; ++jj)
                bfr[jj] = *(const bf16x8*)(const void*)(&sb[boff + jj * 512]);
#pragma unroll
            for (int mi = 0; mi < 4; ++mi)
                af0[mi] = *(const bf16x8*)(const void*)(&sb[aoff + mi * 512]);
            if (g + 3 < GEND) STAGE_A(g + 3);
            asm volatile("s_barrier" ::: "memory");
            asm volatile("s_waitcnt lgkmcnt(0)" ::: "memory");
            __builtin_amdgcn_sched_barrier(0);
            __builtin_amdgcn_s_setprio(1);
#pragma unroll
            for (int mi = 0; mi < 4; ++mi)
#pragma unroll
                for (int jj = 0; jj < 4; ++jj)
                    acc[mi][jj] = __builtin_amdgcn_mfma_f32_16x16x32_bf16(
                        af0[mi], bfr[jj], acc[mi][jj], 0, 0, 0);
            __builtin_amdgcn_s_setprio(0);
            asm volatile("s_barrier" ::: "memory");

            // ---- phase 2: issue A-high reads; stage B-half of g+3 ----
#pragma unroll
            for (int mi = 0; mi < 4; ++mi)
                af1[mi] = *(const bf16x8*)(const void*)(&sb[aoff + (mi + 4) * 512]);
            if (g + 3 < GEND) STAGE_B(g + 3);
            asm volatile("s_barrier" ::: "memory");
            asm volatile("s_waitcnt lgkmcnt(0)" ::: "memory");
            __builtin_amdgcn_sched_barrier(0);
            __builtin_amdgcn_s_setprio(1);
#pragma unroll
            for (int mi = 0; mi < 4; ++mi)
#pragma unroll
                for (int jj = 0; jj < 4; ++jj)
                    acc[mi + 4][jj] = __builtin_amdgcn_mfma_f32_16x16x32_bf16(
                        af1[mi], bfr[jj], acc[mi + 4][jj], 0, 0, 0);
            __builtin_amdgcn_s_setprio(0);

            // end-of-step: counted wait — step g+1 must be resident; keep the
            // deeper prefetch (up to 8 loads) in flight. Never drains mid-run.
            if (g + 1 < GEND) {
                if (g + 4 <= GEND)
                    asm volatile("s_waitcnt vmcnt(8)\n\ts_barrier" ::: "memory");
                else if (g + 3 <= GEND)
                    asm volatile("s_waitcnt vmcnt(4)\n\ts_barrier" ::: "memory");
                else
                    asm volatile("s_waitcnt vmcnt(0)\n\ts_barrier" ::: "memory");
            }
        }

        // ---- epilogue for tile tg (C/D: col=lane&15, row=quad*4+reg) ----
        const int tg  = bid * TPB + tt;
        const int col = tg >> 9;
        const int m0  = (tg & 511) * 256;
        const int m_base = m0 + wm * 128 + quad * 4;
        if (EPI == 0) {
            if (col < 2) {
                const int o0 = col * 128 + wn * 32 + l15;
                const float bI0 = bias[o0],            bI1 = bias[o0 + 16];
                const float bH0 = bias[512 + o0],      bH1 = bias[512 + o0 + 16];
                const int q = (col * 4 + wn) * 16 + l15;      // u32 slot
#pragma unroll
                for (int mi = 0; mi < 8; ++mi) {
#pragma unroll
                    for (int r = 0; r < 4; ++r) {
                        const int m = m_base + mi * 16 + r;
                        const float ig0 = sigm(acc[mi][0][r] + bI0) * fmaxf(acc[mi][2][r] + bH0, 0.f);
                        const float ig1 = sigm(acc[mi][1][r] + bI1) * fmaxf(acc[mi][3][r] + bH1, 0.f);
                        *(u32*)(void*)(Gout + (size_t)m * G2_ + 2 * q) = pack2h(ig0, ig1);
                    }
                }
            } else {
                const int o0 = wn * 64 + l15;
                const float bF0 = bias[256 + o0],       bF1 = bias[256 + o0 + 16];
                const float bF2 = bias[256 + o0 + 32],  bF3 = bias[256 + o0 + 48];
                const int qA = wn * 32 + l15, qB = qA + 16;
#pragma unroll
                for (int mi = 0; mi < 8; ++mi) {
#pragma unroll
                    for (int r = 0; r < 4; ++r) {
                        const int m = m_base + mi * 16 + r;
                        u16* row = Gout + (size_t)m * G2_ + 256;
                        *(u32*)(void*)(row + 2 * qA) =
                            pack2h(sigm(acc[mi][0][r] + bF0), sigm(acc[mi][1][r] + bF1));
                        *(u32*)(void*)(row + 2 * qB) =
                            pack2h(sigm(acc[mi][2][r] + bF2), sigm(acc[mi][3][r] + bF3));
                    }
                }
            }
        } else {
            const int colb = wn * 64 + l15;
            float bb[4];
#pragma unroll
            for (int jj = 0; jj < 4; ++jj) bb[jj] = bias[colb + jj * 16];
#pragma unroll
            for (int mi = 0; mi < 8; ++mi) {
#pragma unroll
                for (int r = 0; r < 4; ++r) {
                    const int m = m_base + mi * 16 + r;
                    const u16* cp = cellbuf + (size_t)m * K_ + 256 + colb;
                    float* op = Out + (size_t)m * N2_ + colb;
#pragma unroll
                    for (int jj = 0; jj < 4; ++jj)
                        op[jj * 16] = sigm(acc[mi][jj][r] + bb[jj]) * bf2f(cp[jj * 16]);
                }
            }
        }
    }
}

// ---- scan phase 1: local recurrence over 64 steps; 4 values/thread ----
// (round-4 geometry: 512 blocks = 8 waves/CU for latency hiding)
__global__ __launch_bounds__(256) void scan_phase1(
    const u16* __restrict__ g2, float* __restrict__ cF, float* __restrict__ cC)
{
    const int blk = blockIdx.x;              // (b*8+h)*8 + chp
    const int chp = blk & 7, bh = blk >> 3;
    const int h = bh & 7, b = bh >> 3;
    const int t = threadIdx.x;
    const int ch = chp * 4 + (t >> 6);
    const int o = (t & 63) * 4;              // storage u16 offset
    float F[4] = {1.f, 1.f, 1.f, 1.f};
    float c[4] = {0.f, 0.f, 0.f, 0.f};
    for (int i = 0; i < 64; ++i) {
        const int s = ch * 64 + i;
        const size_t m = ((size_t)(b * S_ + s)) * H_ + h;
        const u16* gp = g2 + m * G2_;
        const uint2 igp = *(const uint2*)(const void*)(gp + o);
        const uint2 fgp = *(const uint2*)(const void*)(gp + 256 + o);
        const float f0 = h2f((u16)fgp.x), f1 = h2f((u16)(fgp.x >> 16));
        const float f2 = h2f((u16)fgp.y), f3 = h2f((u16)(fgp.y >> 16));
        c[0] = f0 * c[0] + h2f((u16)igp.x);         F[0] *= f0;
        c[1] = f1 * c[1] + h2f((u16)(igp.x >> 16)); F[1] *= f1;
        c[2] = f2 * c[2] + h2f((u16)igp.y);         F[2] *= f2;
        c[3] = f3 * c[3] + h2f((u16)(igp.y >> 16)); F[3] *= f3;
    }
    const size_t idx = ((size_t)(bh * 32 + ch)) * 256 + o;
    *(float4*)(void*)(cF + idx) = make_float4(F[0], F[1], F[2], F[3]);
    *(float4*)(void*)(cC + idx) = make_float4(c[0], c[1], c[2], c[3]);
}

// ---- scan carry combine (storage order; initcx needs real o) ----
__global__ __launch_bounds__(256) void scan_mid(
    const float* __restrict__ cF, const float* __restrict__ cC,
    const float* __restrict__ initcx, float* __restrict__ cin)
{
    const int bh = blockIdx.x;               // b*8 + h
    const int h = bh & 7;
    const int a = threadIdx.x;               // storage position
    const int q = a >> 1, hfl = a & 1;
    const int ro = ((q >> 4) << 5) + (q & 15) + (hfl << 4);  // real o
    float fa[32], ca[32], co[32];
#pragma unroll
    for (int ch = 0; ch < 32; ++ch) {
        const size_t idx = ((size_t)(bh * 32 + ch)) * 256 + a;
        fa[ch] = cF[idx];
        ca[ch] = cC[idx];
    }
    float c = initcx[h * 256 + ro];
#pragma unroll
    for (int ch = 0; ch < 32; ++ch) {
        co[ch] = c;
        c = fa[ch] * c + ca[ch];
    }
#pragma unroll
    for (int ch = 0; ch < 32; ++ch)
        cin[((size_t)(bh * 32 + ch)) * 256 + a] = co[ch];
}

// ---- scan phase 2: replay; write cell bf16 (real o order) into x2 ----
// (round-4 geometry)
__global__ __launch_bounds__(256) void scan_phase2(
    const u16* __restrict__ g2, const float* __restrict__ cin,
    u16* __restrict__ x2)
{
    const int blk = blockIdx.x;
    const int chp = blk & 7, bh = blk >> 3;
    const int h = bh & 7, b = bh >> 3;
    const int t = threadIdx.x;
    const int ch = chp * 4 + (t >> 6);
    const int z = t & 63;
    const int o = z * 4;                     // storage u16 offset
    // storage positions o..o+3 map to real o's: oA, oA+16, oA+1, oA+17
    const int oA = ((z >> 3) << 5) + ((z & 7) << 1);
    const size_t idx = ((size_t)(bh * 32 + ch)) * 256 + o;
    float4 c4 = *(const float4*)(const void*)(cin + idx);
    float c[4] = {c4.x, c4.y, c4.z, c4.w};
    for (int i = 0; i < 64; ++i) {
        const int s = ch * 64 + i;
        const size_t m = ((size_t)(b * S_ + s)) * H_ + h;
        const u16* gp = g2 + m * G2_;
        const uint2 igp = *(const uint2*)(const void*)(gp + o);
        const uint2 fgp = *(const uint2*)(const void*)(gp + 256 + o);
        const float f0 = h2f((u16)fgp.x), f1 = h2f((u16)(fgp.x >> 16));
        const float f2 = h2f((u16)fgp.y), f3 = h2f((u16)(fgp.y >> 16));
        c[0] = f0 * c[0] + h2f((u16)igp.x);
        c[1] = f1 * c[1] + h2f((u16)(igp.x >> 16));
        c[2] = f2 * c[2] + h2f((u16)igp.y);
        c[3] = f3 * c[3] + h2f((u16)(igp.y >> 16));
        u16* xr = x2 + m * K_ + 256;
        const u32 pkA = (u32)f2bf(c[0]) | ((u32)f2bf(c[2]) << 16);  // cols oA, oA+1
        const u32 pkB = (u32)f2bf(c[1]) | ((u32)f2bf(c[3]) << 16);  // cols oA+16, oA+17
        *(u32*)(void*)(xr + oA)      = pkA;
        *(u32*)(void*)(xr + oA + 16) = pkB;
    }
}

extern "C" void kernel_launch(void* const* d_in, const int* in_sizes, int n_in,
                              void* d_out, int out_size, void* d_ws, size_t ws_size,
                              hipStream_t stream)
{
    const float* X      = (const float*)d_in[0];
    const float* Whid   = (const float*)d_in[1];
    const float* bhid   = (const float*)d_in[2];
    const float* Wog    = (const float*)d_in[3];
    const float* bog    = (const float*)d_in[4];
    const float* lnw    = (const float*)d_in[5];
    const float* lnb    = (const float*)d_in[6];
    const float* initcx = (const float*)d_in[7];
    float* out = (float*)d_out;

    char* ws = (char*)d_ws;
    u16* x2   = (u16*)(ws + OFF_X2);
    u16* g    = (u16*)(ws + OFF_G);
    u16* WhB  = (u16*)(ws + OFF_WH);
    u16* WoB  = (u16*)(ws + OFF_WO);
    float* aux = (float*)(ws + OFF_AUX);
    float* cF  = (float*)(ws + OFF_CF);
    float* cC  = (float*)(ws + OFF_CC);
    float* cin = (float*)(ws + OFF_CIN);

    wconv_kernel<<<(N1_*K_ + 255) / 256, 256, 0, stream>>>(Whid, Wog, WhB, WoB);
    csum_phase1<<<B_ * CSCH, 256, 0, stream>>>(X, aux);
    csum_mid<<<64, 256, 0, stream>>>(aux);
    csum_phase2<<<B_ * CSCH, 256, 0, stream>>>(X, aux, lnw, lnb, x2);
    gemm_kernel<N1_, 0><<<256, 512, 0, stream>>>(
        x2, WhB, g, bhid, nullptr, nullptr);
    scan_phase1<<<B_ * H_ * 8, 256, 0, stream>>>(g, cF, cC);
    scan_mid<<<B_ * H_, 256, 0, stream>>>(cF, cC, initcx, cin);
    scan_phase2<<<B_ * H_ * 8, 256, 0, stream>>>(g, cin, x2);
    gemm_kernel<N2_, 1><<<256, 512, 0, stream>>>(
        x2, WoB, nullptr, bog, x2, out);
}